// Round 3
// baseline (13053.499 us; speedup 1.0000x reference)
//
#include <hip/hip_runtime.h>

typedef _Float16 f16x8 __attribute__((ext_vector_type(8)));
typedef float f32x4 __attribute__((ext_vector_type(4)));

static constexpr int NL = 5;
static constexpr int NBATCH = 256;
static constexpr int NT = 128;
static constexpr int NH = 512;
static constexpr int NG = 2048;   // 4*NH
static constexpr int NC = 40;
static constexpr int NBLK = 160;  // 5 layers x 32 col-blocks
static constexpr int PLANE = NBATCH * NH;  // 131072 (pow2)

// ---------------------------------------------------------------------------
__global__ void f32_to_f16_kernel(const float* __restrict__ src,
                                  _Float16* __restrict__ dst, int n) {
  int i = blockIdx.x * blockDim.x + threadIdx.x;
  int stride = gridDim.x * blockDim.x;
  for (; i < n; i += stride) dst[i] = (_Float16)src[i];
}

// ---------------------------------------------------------------------------
// Persistent LSTM: 160 blocks co-resident (128KB LDS each -> 1 block/CU).
// Block (layer, nb): owns units [nb*16, nb*16+16), all 4 gates = 64 gate-rows.
// Weights fp16 in LDS for the whole run; c-state in registers; h via global
// with a hand-rolled device-scope grid barrier per pipeline slot.
// wlds row layout: wrow = g*16 + j (gate g, unit j); cols 0..511 = Wih row,
// 512..1023 = Whh row; 16B-chunk XOR-swizzle by (wrow&7)<<4.
// ---------------------------------------------------------------------------
__global__ __launch_bounds__(512, 2) void lstm_persist(
    const float* __restrict__ Wih, const float* __restrict__ Whh,
    const _Float16* __restrict__ x_h, const float* __restrict__ bih,
    const float* __restrict__ bhh, _Float16* __restrict__ h_xfer,
    unsigned* __restrict__ bar_cnt) {
  extern __shared__ _Float16 wlds[];  // [64][1024] fp16, swizzled = 128 KB

  const int bid = blockIdx.x;
  const int layer = bid >> 5;
  const int nb = bid & 31;
  const int tid = threadIdx.x;
  const int lane = tid & 63;
  const int wv = tid >> 6;
  const int mq = wv >> 1;    // 0..3 : 64-row batch group
  const int nq = wv & 1;     // 0..1 : 8-unit group
  const int lrow = lane & 15;
  const int lk = (lane >> 4) << 3;     // 0,8,16,24
  const int swz = (lane & 7) << 4;
  const int m0 = mq * 64;

  // ---- stage this block's weights into LDS (once) ----
  {
    const float* wi = Wih + (size_t)layer * NG * NH;
    const float* wh = Whh + (size_t)layer * NG * NH;
    for (int c = tid; c < 64 * 128; c += 512) {
      const int wrow = c >> 7;       // 0..63
      const int k16 = c & 127;       // 16B chunk index in 2KB row
      const int g = wrow >> 4, j = wrow & 15;
      const size_t grow = (size_t)(g * NH + nb * 16 + j) * NH;
      const float* src =
          (k16 < 64) ? (wi + grow + k16 * 8) : (wh + grow + (k16 - 64) * 8);
      f16x8 v;
#pragma unroll
      for (int e = 0; e < 8; ++e) v[e] = (_Float16)src[e];
      const int boff = wrow * 2048 + ((k16 * 16) ^ ((wrow & 7) << 4));
      *(f16x8*)((char*)wlds + boff) = v;
    }
  }

  // ---- zero parity-1 h planes ----
  for (int i = bid * 512 + tid; i < NL * PLANE; i += NBLK * 512) {
    const int l = i >> 17;             // /PLANE
    const int off = i & (PLANE - 1);
    h_xfer[(size_t)(l * 2 + 1) * PLANE + off] = (_Float16)0.f;
  }

  // ---- per-lane constants ----
  const int u_loc = nq * 8 + (lane & 7);
  const int u = nb * 16 + u_loc;
  const float bs0 = bih[layer * NG + 0 * NH + u] + bhh[layer * NG + 0 * NH + u];
  const float bs1 = bih[layer * NG + 1 * NH + u] + bhh[layer * NG + 1 * NH + u];
  const float bs2 = bih[layer * NG + 2 * NH + u] + bhh[layer * NG + 2 * NH + u];
  const float bs3 = bih[layer * NG + 3 * NH + u] + bhh[layer * NG + 3 * NH + u];

  // B-fragment LDS row bases: tile nt covers gates {2nt, 2nt+1} x 8 units
  const int wrow0 = ((lrow >> 3) + 0) * 16 + u_loc;  // gates 0/1
  const int wrow1 = ((lrow >> 3) + 2) * 16 + u_loc;  // gates 2/3
  const int wb0 = wrow0 * 2048;
  const int wb1 = wrow1 * 2048;

  float cst[8];
#pragma unroll
  for (int i = 0; i < 8; ++i) cst[i] = 0.f;

  __syncthreads();

  // ---- slot loop ----
  for (int s = 0; s < NT + NL - 1; ++s) {
    const int t = s - layer;
    if (t >= 0 && t < NT) {
      f32x4 acc[4][2];
#pragma unroll
      for (int i = 0; i < 4; ++i)
#pragma unroll
        for (int j = 0; j < 2; ++j) acc[i][j] = (f32x4){0.f, 0.f, 0.f, 0.f};

      auto do_half = [&](const _Float16* aptr, size_t astr, int kbase) {
        const _Float16* ar = aptr + (size_t)(m0 + lrow) * astr + lk;
#pragma unroll 2
        for (int kk = 0; kk < 16; ++kk) {
          const int kc = kk << 5;
          f16x8 a0 = *(const f16x8*)(ar + kc);
          f16x8 a1 = *(const f16x8*)(ar + 16 * astr + kc);
          f16x8 a2 = *(const f16x8*)(ar + 32 * astr + kc);
          f16x8 a3 = *(const f16x8*)(ar + 48 * astr + kc);
          const int ko = ((lk + kc + kbase) << 1) ^ swz;
          f16x8 b0 = *(const f16x8*)((const char*)wlds + wb0 + ko);
          f16x8 b1 = *(const f16x8*)((const char*)wlds + wb1 + ko);
          acc[0][0] = __builtin_amdgcn_mfma_f32_16x16x32_f16(a0, b0, acc[0][0], 0, 0, 0);
          acc[1][0] = __builtin_amdgcn_mfma_f32_16x16x32_f16(a1, b0, acc[1][0], 0, 0, 0);
          acc[2][0] = __builtin_amdgcn_mfma_f32_16x16x32_f16(a2, b0, acc[2][0], 0, 0, 0);
          acc[3][0] = __builtin_amdgcn_mfma_f32_16x16x32_f16(a3, b0, acc[3][0], 0, 0, 0);
          acc[0][1] = __builtin_amdgcn_mfma_f32_16x16x32_f16(a0, b1, acc[0][1], 0, 0, 0);
          acc[1][1] = __builtin_amdgcn_mfma_f32_16x16x32_f16(a1, b1, acc[1][1], 0, 0, 0);
          acc[2][1] = __builtin_amdgcn_mfma_f32_16x16x32_f16(a2, b1, acc[2][1], 0, 0, 0);
          acc[3][1] = __builtin_amdgcn_mfma_f32_16x16x32_f16(a3, b1, acc[3][1], 0, 0, 0);
        }
      };

      // half 0: layer input (x for layer 0, else prev layer h), LDS cols 0..511
      if (layer == 0) {
        do_half(x_h + (size_t)t * NH, (size_t)NT * NH, 0);
      } else {
        do_half(h_xfer + (size_t)((layer - 1) * 2 + (t & 1)) * PLANE,
                (size_t)NH, 0);
      }
      // half 1: own h_prev, LDS cols 512..1023 (skip at t==0: h_prev == 0)
      if (t > 0) {
        do_half(h_xfer + (size_t)(layer * 2 + ((t - 1) & 1)) * PLANE,
                (size_t)NH, 512);
      }

      // ---- in-wave gate exchange + cell update + h write ----
      _Float16* hout = h_xfer + (size_t)(layer * 2 + (t & 1)) * PLANE;
      const int rbase = (lane & 8) ? 2 : 0;
#pragma unroll
      for (int mt = 0; mt < 4; ++mt) {
#pragma unroll
        for (int rr = 0; rr < 2; ++rr) {
          float own0 = acc[mt][0][rbase + rr];
          float own1 = acc[mt][1][rbase + rr];
          float snd0 = (lane & 8) ? acc[mt][0][rr] : acc[mt][0][2 + rr];
          float snd1 = (lane & 8) ? acc[mt][1][rr] : acc[mt][1][2 + rr];
          float rcv0 = __shfl_xor(snd0, 8);
          float rcv1 = __shfl_xor(snd1, 8);
          float gi = ((lane & 8) ? rcv0 : own0) + bs0;
          float gf = ((lane & 8) ? own0 : rcv0) + bs1;
          float gg = ((lane & 8) ? rcv1 : own1) + bs2;
          float go = ((lane & 8) ? own1 : rcv1) + bs3;
          float cp = cst[mt * 2 + rr];
          float is = 1.f / (1.f + __expf(-gi));
          float fs = 1.f / (1.f + __expf(-gf));
          float gt = 2.f / (1.f + __expf(-2.f * gg)) - 1.f;
          float os = 1.f / (1.f + __expf(-go));
          float c = fs * cp + is * gt;
          cst[mt * 2 + rr] = c;
          float th = 2.f / (1.f + __expf(-2.f * c)) - 1.f;
          const int row = m0 + mt * 16 + ((lane >> 4) << 2) + rbase + rr;
          hout[(size_t)row * NH + u] = (_Float16)(os * th);
        }
      }
    }

    // ---- grid barrier (device scope) ----
    __threadfence();   // release: drain stores
    __syncthreads();
    if (tid == 0) {
      atomicAdd(bar_cnt, 1u);
      const unsigned tgt = (unsigned)(s + 1) * NBLK;
      int guard = 0;
      while (__hip_atomic_load(bar_cnt, __ATOMIC_RELAXED,
                               __HIP_MEMORY_SCOPE_AGENT) < tgt) {
        __builtin_amdgcn_s_sleep(2);
        if (++guard > 200000000) break;  // anti-deadlock escape
      }
    }
    __syncthreads();
    __threadfence();   // acquire: invalidate stale cached lines
  }
}

// ---------------------------------------------------------------------------
__global__ __launch_bounds__(64) void fc_kernel(
    const _Float16* __restrict__ h_xfer, const float* __restrict__ wfc,
    const float* __restrict__ bfc, float* __restrict__ out) {
  const _Float16* h = h_xfer + (size_t)(4 * 2 + 1) * PLANE;  // layer 4, t=127
  const int b = blockIdx.x;
  const int lane = threadIdx.x;
  __shared__ float hrow[NH];
  for (int k = lane; k < NH; k += 64) hrow[k] = (float)h[(size_t)b * NH + k];
  __syncthreads();
  if (lane < NC) {
    const float* w = wfc + (size_t)lane * NH;
    float acc = bfc[lane];
#pragma unroll 8
    for (int k = 0; k < NH; ++k) acc += hrow[k] * w[k];
    out[b * NC + lane] = acc;
  }
}

// ---------------------------------------------------------------------------
extern "C" void kernel_launch(void* const* d_in, const int* in_sizes, int n_in,
                              void* d_out, int out_size, void* d_ws,
                              size_t ws_size, hipStream_t stream) {
  const float* x = (const float*)d_in[0];
  const float* Wih = (const float*)d_in[1];
  const float* Whh = (const float*)d_in[2];
  const float* bih = (const float*)d_in[3];
  const float* bhh = (const float*)d_in[4];
  const float* Wfc = (const float*)d_in[5];
  const float* bfc = (const float*)d_in[6];
  float* out = (float*)d_out;

  char* ws = (char*)d_ws;
  size_t off = 0;
  _Float16* x_h = (_Float16*)(ws + off);
  off += (size_t)NBATCH * NT * NH * 2;
  _Float16* h_xfer = (_Float16*)(ws + off);
  off += (size_t)NL * 2 * PLANE * 2;
  off = (off + 255) & ~(size_t)255;
  unsigned* bar_cnt = (unsigned*)(ws + off);
  off += 256;

  hipFuncSetAttribute((const void*)lstm_persist,
                      hipFuncAttributeMaxDynamicSharedMemorySize, 131072);

  f32_to_f16_kernel<<<2048, 256, 0, stream>>>(x, x_h, NBATCH * NT * NH);
  hipMemsetAsync(bar_cnt, 0, 256, stream);

  lstm_persist<<<NBLK, 512, 131072, stream>>>(Wih, Whh, x_h, bih, bhh, h_xfer,
                                              bar_cnt);

  fc_kernel<<<NBATCH, 64, 0, stream>>>(h_xfer, Wfc, bfc, out);
}

// Round 4
// 12467.706 us; speedup vs baseline: 1.0470x; 1.0470x over previous
//
#include <hip/hip_runtime.h>

typedef _Float16 f16x8 __attribute__((ext_vector_type(8)));
typedef float f32x4 __attribute__((ext_vector_type(4)));

static constexpr int NL = 5;
static constexpr int NBATCH = 256;
static constexpr int NT = 128;
static constexpr int NH = 512;
static constexpr int NG = 2048;       // 4*NH
static constexpr int NC = 40;
static constexpr int GRID = 256;      // 1 block per CU; layer = bid&7 (XCD pin)
static constexpr int PL = 32 * 256 * 16;  // plane elems (tiled [ub][b][16])

// ---------------------------------------------------------------------------
// x [B][T][I] fp32  ->  xt planes [T][ub 32][b 256][16] fp16
// One block per (t, ub) tile: reads 16B/lane strided, writes contiguous.
// ---------------------------------------------------------------------------
__global__ __launch_bounds__(64) void x_tile_kernel(
    const float* __restrict__ x, _Float16* __restrict__ xt) {
  const int tile = blockIdx.x;          // 0..4095
  const int t = tile >> 5;
  const int ub = tile & 31;
  const int lane = threadIdx.x;
#pragma unroll
  for (int rep = 0; rep < 4; ++rep) {
    const int b = rep * 64 + lane;
    const float* src = x + ((size_t)b * NT + t) * NH + ub * 16;
    _Float16* dst = xt + (size_t)t * PL + ub * 4096 + b * 16;
    f16x8 v0, v1;
#pragma unroll
    for (int e = 0; e < 8; ++e) {
      v0[e] = (_Float16)src[e];
      v1[e] = (_Float16)src[8 + e];
    }
    *(f16x8*)dst = v0;
    *(f16x8*)(dst + 8) = v1;
  }
}

// ---------------------------------------------------------------------------
// Persistent LSTM. 256 blocks (1/CU forced by 128KB LDS). layer = bid&7
// (blocks of one layer share an XCD under round-robin dispatch); layer>=5
// blocks are barrier-only. nb = bid>>3 selects 16 units.
// Weights fp16 in LDS (64 rows x 1024 cols, XOR-swizzled); c in registers;
// h planes in global, tiled [ub][b][16] so A-loads are contiguous 1KB.
// Wave w handles rows [w*32, w*32+32), all 4 gates x 16 units; cell update
// is lane-local (gates 0..3 = acc n-tiles 0..3 in the same lane).
// ---------------------------------------------------------------------------
__global__ __launch_bounds__(512, 2) void lstm_persist(
    const float* __restrict__ Wih, const float* __restrict__ Whh,
    const _Float16* __restrict__ xt, const float* __restrict__ bih,
    const float* __restrict__ bhh, _Float16* __restrict__ hpl,
    unsigned* __restrict__ bar_cnt) {
  extern __shared__ _Float16 wlds[];  // 64 rows x 2048 B = 128 KB

  const int bid = blockIdx.x;
  const int layer = bid & 7;
  const int nb = bid >> 3;
  const bool active = layer < NL;
  const int tid = threadIdx.x;
  const int lane = tid & 63;
  const int w = tid >> 6;
  const int rowbase = w * 32;
  const int j = lane & 15;
  const int swz = (j & 7) << 4;

  // ---- stage weights (once): wrow = g*16 + j2, cols 0..511 Wih, 512..1023 Whh
  if (active) {
    const float* wi = Wih + (size_t)layer * NG * NH;
    const float* wh = Whh + (size_t)layer * NG * NH;
    for (int c = tid; c < 64 * 128; c += 512) {
      const int wrow = c >> 7;
      const int k16 = c & 127;
      const int g = wrow >> 4, j2 = wrow & 15;
      const size_t grow = (size_t)(g * NH + nb * 16 + j2) * NH;
      const float* src =
          (k16 < 64) ? (wi + grow + k16 * 8) : (wh + grow + (k16 - 64) * 8);
      f16x8 v;
#pragma unroll
      for (int e = 0; e < 8; ++e) v[e] = (_Float16)src[e];
      const int boff = wrow * 2048 + ((k16 * 16) ^ ((wrow & 7) << 4));
      *(f16x8*)((char*)wlds + boff) = v;
    }
  }

  // ---- per-lane constants ----
  const int u = nb * 16 + j;
  float bs0 = 0.f, bs1 = 0.f, bs2 = 0.f, bs3 = 0.f;
  if (active) {
    bs0 = bih[layer * NG + 0 * NH + u] + bhh[layer * NG + 0 * NH + u];
    bs1 = bih[layer * NG + 1 * NH + u] + bhh[layer * NG + 1 * NH + u];
    bs2 = bih[layer * NG + 2 * NH + u] + bhh[layer * NG + 2 * NH + u];
    bs3 = bih[layer * NG + 3 * NH + u] + bhh[layer * NG + 3 * NH + u];
  }

  // A-lane offset (halves) into a tiled plane; + kk*8192 + mt*256 per frag
  const int aoff = rowbase * 16 + j * 16 + (lane >> 5) * 4096 +
                   ((lane >> 4) & 1) * 8;
  // B LDS byte bases per n-tile (gate) and per-lane col base
  const int bb0 = (0 * 16 + j) * 2048;
  const int bb1 = (1 * 16 + j) * 2048;
  const int bb2 = (2 * 16 + j) * 2048;
  const int bb3 = (3 * 16 + j) * 2048;
  const int bcol0 = (lane >> 4) * 16;

  float cst[8];
#pragma unroll
  for (int i = 0; i < 8; ++i) cst[i] = 0.f;

  __syncthreads();

  for (int s = 0; s < NT + NL - 1; ++s) {
    const int t = active ? (s - layer) : -1;
    if (t >= 0 && t < NT) {
      f32x4 acc[2][4];
#pragma unroll
      for (int m = 0; m < 2; ++m)
#pragma unroll
        for (int n = 0; n < 4; ++n) acc[m][n] = (f32x4){0.f, 0.f, 0.f, 0.f};

      auto do_half = [&](const _Float16* __restrict__ Abase, int hbase) {
#pragma unroll 4
        for (int kk = 0; kk < 16; ++kk) {
          const _Float16* ap = Abase + aoff + kk * 8192;
          f16x8 a0 = *(const f16x8*)(ap);
          f16x8 a1 = *(const f16x8*)(ap + 256);
          const int ko = ((kk << 6) + hbase + bcol0) ^ swz;
          f16x8 b0 = *(const f16x8*)((const char*)wlds + bb0 + ko);
          f16x8 b1 = *(const f16x8*)((const char*)wlds + bb1 + ko);
          f16x8 b2 = *(const f16x8*)((const char*)wlds + bb2 + ko);
          f16x8 b3 = *(const f16x8*)((const char*)wlds + bb3 + ko);
          acc[0][0] = __builtin_amdgcn_mfma_f32_16x16x32_f16(a0, b0, acc[0][0], 0, 0, 0);
          acc[1][0] = __builtin_amdgcn_mfma_f32_16x16x32_f16(a1, b0, acc[1][0], 0, 0, 0);
          acc[0][1] = __builtin_amdgcn_mfma_f32_16x16x32_f16(a0, b1, acc[0][1], 0, 0, 0);
          acc[1][1] = __builtin_amdgcn_mfma_f32_16x16x32_f16(a1, b1, acc[1][1], 0, 0, 0);
          acc[0][2] = __builtin_amdgcn_mfma_f32_16x16x32_f16(a0, b2, acc[0][2], 0, 0, 0);
          acc[1][2] = __builtin_amdgcn_mfma_f32_16x16x32_f16(a1, b2, acc[1][2], 0, 0, 0);
          acc[0][3] = __builtin_amdgcn_mfma_f32_16x16x32_f16(a0, b3, acc[0][3], 0, 0, 0);
          acc[1][3] = __builtin_amdgcn_mfma_f32_16x16x32_f16(a1, b3, acc[1][3], 0, 0, 0);
        }
      };

      // half 0: layer input (x tiles for layer 0, else prev-layer h plane)
      if (layer == 0) {
        do_half(xt + (size_t)t * PL, 0);
      } else {
        do_half(hpl + (size_t)((layer - 1) * 2 + (t & 1)) * PL, 0);
      }
      // half 1: own h_prev (zero at t==0 -> skip)
      if (t > 0) {
        do_half(hpl + (size_t)(layer * 2 + ((t - 1) & 1)) * PL, 1024);
      }

      // ---- lane-local cell update + h write ----
      _Float16* hout = hpl + (size_t)(layer * 2 + (t & 1)) * PL + nb * 4096;
#pragma unroll
      for (int mt = 0; mt < 2; ++mt) {
#pragma unroll
        for (int r = 0; r < 4; ++r) {
          float gi = acc[mt][0][r] + bs0;
          float gf = acc[mt][1][r] + bs1;
          float gg = acc[mt][2][r] + bs2;
          float go = acc[mt][3][r] + bs3;
          float cp = cst[mt * 4 + r];
          float is = 1.f / (1.f + __expf(-gi));
          float fs = 1.f / (1.f + __expf(-gf));
          float gt = 2.f / (1.f + __expf(-2.f * gg)) - 1.f;
          float os = 1.f / (1.f + __expf(-go));
          float c = fs * cp + is * gt;
          cst[mt * 4 + r] = c;
          float th = 2.f / (1.f + __expf(-2.f * c)) - 1.f;
          const int row = rowbase + mt * 16 + ((lane >> 4) << 2) + r;
          hout[row * 16 + j] = (_Float16)(os * th);
        }
      }
    }

    // ---- device-scope grid barrier ----
    __threadfence();   // release: drain + write back h stores
    __syncthreads();
    if (tid == 0) {
      atomicAdd(bar_cnt, 1u);
      const unsigned tgt = (unsigned)(s + 1) * GRID;
      int guard = 0;
      while (__hip_atomic_load(bar_cnt, __ATOMIC_RELAXED,
                               __HIP_MEMORY_SCOPE_AGENT) < tgt) {
        __builtin_amdgcn_s_sleep(2);
        if (++guard > 200000000) break;
      }
    }
    __syncthreads();
    __threadfence();   // acquire: invalidate stale L2 lines
  }
}

// ---------------------------------------------------------------------------
__global__ __launch_bounds__(64) void fc_kernel(
    const _Float16* __restrict__ hpl, const float* __restrict__ wfc,
    const float* __restrict__ bfc, float* __restrict__ out) {
  const _Float16* h = hpl + (size_t)9 * PL;  // layer 4, parity (127&1)=1
  const int b = blockIdx.x;
  const int lane = threadIdx.x;
  __shared__ float hrow[NH];
  for (int k = lane; k < NH; k += 64)
    hrow[k] = (float)h[(k >> 4) * 4096 + b * 16 + (k & 15)];
  __syncthreads();
  if (lane < NC) {
    const float* wv = wfc + (size_t)lane * NH;
    float acc = bfc[lane];
#pragma unroll 8
    for (int k = 0; k < NH; ++k) acc += hrow[k] * wv[k];
    out[b * NC + lane] = acc;
  }
}

// ---------------------------------------------------------------------------
extern "C" void kernel_launch(void* const* d_in, const int* in_sizes, int n_in,
                              void* d_out, int out_size, void* d_ws,
                              size_t ws_size, hipStream_t stream) {
  const float* x = (const float*)d_in[0];
  const float* Wih = (const float*)d_in[1];
  const float* Whh = (const float*)d_in[2];
  const float* bih = (const float*)d_in[3];
  const float* bhh = (const float*)d_in[4];
  const float* Wfc = (const float*)d_in[5];
  const float* bfc = (const float*)d_in[6];
  float* out = (float*)d_out;

  char* ws = (char*)d_ws;
  size_t off = 0;
  _Float16* xt = (_Float16*)(ws + off);
  off += (size_t)NT * PL * 2;           // 33.5 MB
  _Float16* hpl = (_Float16*)(ws + off);
  off += (size_t)NL * 2 * PL * 2;       // 2.6 MB
  off = (off + 255) & ~(size_t)255;
  unsigned* bar_cnt = (unsigned*)(ws + off);
  off += 256;

  hipFuncSetAttribute((const void*)lstm_persist,
                      hipFuncAttributeMaxDynamicSharedMemorySize, 131072);

  x_tile_kernel<<<NT * 32, 64, 0, stream>>>(x, xt);
  hipMemsetAsync(bar_cnt, 0, 256, stream);

  lstm_persist<<<GRID, 512, 131072, stream>>>(Wih, Whh, xt, bih, bhh, hpl,
                                              bar_cnt);

  fc_kernel<<<NBATCH, 64, 0, stream>>>(hpl, Wfc, bfc, out);
}

// Round 5
// 7802.525 us; speedup vs baseline: 1.6730x; 1.5979x over previous
//
#include <hip/hip_runtime.h>

typedef _Float16 f16x8 __attribute__((ext_vector_type(8)));
typedef float f32x4 __attribute__((ext_vector_type(4)));

static constexpr int NL = 5;
static constexpr int NBATCH = 256;
static constexpr int NT = 128;
static constexpr int NH = 512;
static constexpr int NG = 2048;       // 4*NH
static constexpr int NC = 40;
static constexpr int GRID = 256;      // layer = bid&7 (XCD round-robin pin)
static constexpr int LBLK = 32;       // blocks per layer
static constexpr int PL = 32 * 256 * 16;  // plane elems, tiled [ub 32][b 256][16]
static constexpr int NPAR = 4;        // h parity depth

// ---------------------------------------------------------------------------
// x [B][T][I] fp32 -> xt planes [T][ub][b][16] fp16 (read-only thereafter)
// ---------------------------------------------------------------------------
__global__ __launch_bounds__(64) void x_tile_kernel(
    const float* __restrict__ x, _Float16* __restrict__ xt) {
  const int tile = blockIdx.x;          // 0..4095
  const int t = tile >> 5;
  const int ub = tile & 31;
  const int lane = threadIdx.x;
#pragma unroll
  for (int rep = 0; rep < 4; ++rep) {
    const int b = rep * 64 + lane;
    const float* src = x + ((size_t)b * NT + t) * NH + ub * 16;
    _Float16* dst = xt + (size_t)t * PL + ub * 4096 + b * 16;
    f16x8 v0, v1;
#pragma unroll
    for (int e = 0; e < 8; ++e) {
      v0[e] = (_Float16)src[e];
      v1[e] = (_Float16)src[8 + e];
    }
    *(f16x8*)dst = v0;
    *(f16x8*)(dst + 8) = v1;
  }
}

// ---------------------------------------------------------------------------
// Coherent (LLC-home, sc1) helpers: no cache-wide fences needed anywhere.
// ---------------------------------------------------------------------------
__device__ __forceinline__ f16x8 lda_coh(const void* p) {
  const unsigned* q = (const unsigned*)p;
  union { f16x8 v; unsigned u[4]; } r;
#pragma unroll
  for (int e = 0; e < 4; ++e)
    r.u[e] = __hip_atomic_load(q + e, __ATOMIC_RELAXED, __HIP_MEMORY_SCOPE_AGENT);
  return r.v;
}

__device__ __forceinline__ void wait_ge(unsigned* p, unsigned tgt) {
  long g = 0;
  while (__hip_atomic_load(p, __ATOMIC_RELAXED, __HIP_MEMORY_SCOPE_AGENT) < tgt) {
    __builtin_amdgcn_s_sleep(16);
    if (++g > 60000000L) break;  // anti-hang escape
  }
}

// One K=512 half: depth-4 prefetched A (coherent or plain), B from LDS, 8 MFMA/kk.
template <bool COH>
__device__ __forceinline__ void do_half(
    const _Float16* __restrict__ Abase, int aoff, const _Float16* wlds,
    int bb0, int bb1, int bb2, int bb3, int koff, int swz, f32x4 (&acc)[2][4]) {
  const char* ap = (const char*)(Abase + aoff);
  f16x8 A0[16], A1[16];
#pragma unroll
  for (int kk = 0; kk < 4; ++kk) {
    if (COH) {
      A0[kk] = lda_coh(ap + kk * 16384);
      A1[kk] = lda_coh(ap + kk * 16384 + 512);
    } else {
      A0[kk] = *(const f16x8*)(ap + kk * 16384);
      A1[kk] = *(const f16x8*)(ap + kk * 16384 + 512);
    }
  }
#pragma unroll
  for (int kk = 0; kk < 16; ++kk) {
    if (kk + 4 < 16) {
      if (COH) {
        A0[kk + 4] = lda_coh(ap + (kk + 4) * 16384);
        A1[kk + 4] = lda_coh(ap + (kk + 4) * 16384 + 512);
      } else {
        A0[kk + 4] = *(const f16x8*)(ap + (kk + 4) * 16384);
        A1[kk + 4] = *(const f16x8*)(ap + (kk + 4) * 16384 + 512);
      }
    }
    const int ko = ((kk << 6) + koff) ^ swz;
    f16x8 b0 = *(const f16x8*)((const char*)wlds + bb0 + ko);
    f16x8 b1 = *(const f16x8*)((const char*)wlds + bb1 + ko);
    f16x8 b2 = *(const f16x8*)((const char*)wlds + bb2 + ko);
    f16x8 b3 = *(const f16x8*)((const char*)wlds + bb3 + ko);
    acc[0][0] = __builtin_amdgcn_mfma_f32_16x16x32_f16(A0[kk], b0, acc[0][0], 0, 0, 0);
    acc[1][0] = __builtin_amdgcn_mfma_f32_16x16x32_f16(A1[kk], b0, acc[1][0], 0, 0, 0);
    acc[0][1] = __builtin_amdgcn_mfma_f32_16x16x32_f16(A0[kk], b1, acc[0][1], 0, 0, 0);
    acc[1][1] = __builtin_amdgcn_mfma_f32_16x16x32_f16(A1[kk], b1, acc[1][1], 0, 0, 0);
    acc[0][2] = __builtin_amdgcn_mfma_f32_16x16x32_f16(A0[kk], b2, acc[0][2], 0, 0, 0);
    acc[1][2] = __builtin_amdgcn_mfma_f32_16x16x32_f16(A1[kk], b2, acc[1][2], 0, 0, 0);
    acc[0][3] = __builtin_amdgcn_mfma_f32_16x16x32_f16(A0[kk], b3, acc[0][3], 0, 0, 0);
    acc[1][3] = __builtin_amdgcn_mfma_f32_16x16x32_f16(A1[kk], b3, acc[1][3], 0, 0, 0);
  }
}

// ---------------------------------------------------------------------------
// Persistent async-dataflow LSTM. 256 blocks, 1/CU (128KB LDS). layer=bid&7
// (XCD pin; layers 5-7 exit). Per-layer single-counter phase barrier; h planes
// are LLC-homed via relaxed agent atomics (sc1) -> zero cache-wide fences.
// ---------------------------------------------------------------------------
__global__ __launch_bounds__(512, 2) void lstm_persist(
    const float* __restrict__ Wih, const float* __restrict__ Whh,
    const _Float16* __restrict__ xt, const float* __restrict__ bih,
    const float* __restrict__ bhh, _Float16* __restrict__ hpl,
    unsigned* __restrict__ cnt) {
  extern __shared__ _Float16 wlds[];  // 64 rows x 2048 B = 128 KB

  const int bid = blockIdx.x;
  const int layer = bid & 7;
  if (layer >= NL) return;            // 96 barrier-free idle blocks exit
  const int nb = bid >> 3;
  const int tid = threadIdx.x;
  const int lane = tid & 63;
  const int w = tid >> 6;
  const int rowbase = w * 32;
  const int j = lane & 15;
  const int swz = (j & 7) << 4;

  // ---- stage weights into LDS (once) ----
  {
    const float* wi = Wih + (size_t)layer * NG * NH;
    const float* wh = Whh + (size_t)layer * NG * NH;
    for (int c = tid; c < 64 * 128; c += 512) {
      const int wrow = c >> 7;
      const int k16 = c & 127;
      const int g = wrow >> 4, j2 = wrow & 15;
      const size_t grow = (size_t)(g * NH + nb * 16 + j2) * NH;
      const float* src =
          (k16 < 64) ? (wi + grow + k16 * 8) : (wh + grow + (k16 - 64) * 8);
      f16x8 v;
#pragma unroll
      for (int e = 0; e < 8; ++e) v[e] = (_Float16)src[e];
      const int boff = wrow * 2048 + ((k16 * 16) ^ ((wrow & 7) << 4));
      *(f16x8*)((char*)wlds + boff) = v;
    }
  }

  // ---- per-lane constants ----
  const int u = nb * 16 + j;
  const float bs0 = bih[layer * NG + 0 * NH + u] + bhh[layer * NG + 0 * NH + u];
  const float bs1 = bih[layer * NG + 1 * NH + u] + bhh[layer * NG + 1 * NH + u];
  const float bs2 = bih[layer * NG + 2 * NH + u] + bhh[layer * NG + 2 * NH + u];
  const float bs3 = bih[layer * NG + 3 * NH + u] + bhh[layer * NG + 3 * NH + u];

  const int aoff = rowbase * 16 + j * 16 + (lane >> 5) * 4096 +
                   ((lane >> 4) & 1) * 8;
  const int bb0 = (0 * 16 + j) * 2048;
  const int bb1 = (1 * 16 + j) * 2048;
  const int bb2 = (2 * 16 + j) * 2048;
  const int bb3 = (3 * 16 + j) * 2048;
  const int bcol0 = (lane >> 4) * 16;   // bytes

  unsigned* cown = cnt + layer * 16;
  unsigned* cup = cnt + (layer - 1) * 16;
  unsigned* cdown = cnt + (layer + 1) * 16;

  float cst[8];
#pragma unroll
  for (int i = 0; i < 8; ++i) cst[i] = 0.f;

  __syncthreads();

  for (int t = 0; t < NT; ++t) {
    // ---- dependency waits (tid 0 only; no fences) ----
    if (tid == 0) {
      if (t > 0) wait_ge(cown, (unsigned)(LBLK * t));             // siblings done t-1
      if (layer > 0) wait_ge(cup, (unsigned)(LBLK * (t + 1)));    // upstream done t
      if (layer < NL - 1 && t >= NPAR)
        wait_ge(cdown, (unsigned)(LBLK * (t - NPAR + 1)));        // anti-overwrite
    }
    __syncthreads();

    f32x4 acc[2][4];
#pragma unroll
    for (int m = 0; m < 2; ++m)
#pragma unroll
      for (int n = 0; n < 4; ++n) acc[m][n] = (f32x4){0.f, 0.f, 0.f, 0.f};

    // half 0: layer input
    if (layer == 0)
      do_half<false>(xt + (size_t)t * PL, aoff, wlds, bb0, bb1, bb2, bb3,
                     bcol0, swz, acc);
    else
      do_half<true>(hpl + ((size_t)(layer - 1) * NPAR + (t & 3)) * PL, aoff,
                    wlds, bb0, bb1, bb2, bb3, bcol0, swz, acc);
    // half 1: own h_prev (skip at t==0)
    if (t > 0)
      do_half<true>(hpl + ((size_t)layer * NPAR + ((t - 1) & 3)) * PL, aoff,
                    wlds, bb0, bb1, bb2, bb3, 1024 + bcol0, swz, acc);

    // ---- lane-local cell update + coherent h write ----
    _Float16* hout =
        hpl + ((size_t)layer * NPAR + (t & 3)) * PL + nb * 4096;
#pragma unroll
    for (int mt = 0; mt < 2; ++mt) {
#pragma unroll
      for (int r = 0; r < 4; ++r) {
        float gi = acc[mt][0][r] + bs0;
        float gf = acc[mt][1][r] + bs1;
        float gg = acc[mt][2][r] + bs2;
        float go = acc[mt][3][r] + bs3;
        float cp = cst[mt * 4 + r];
        float is = 1.f / (1.f + __expf(-gi));
        float fs = 1.f / (1.f + __expf(-gf));
        float gt = 2.f / (1.f + __expf(-2.f * gg)) - 1.f;
        float os = 1.f / (1.f + __expf(-go));
        float c = fs * cp + is * gt;
        cst[mt * 4 + r] = c;
        float th = 2.f / (1.f + __expf(-2.f * c)) - 1.f;
        const int row = rowbase + mt * 16 + ((lane >> 4) << 2) + r;
        union { _Float16 f; unsigned short s; } cv;
        cv.f = (_Float16)(os * th);
        __hip_atomic_store((unsigned short*)(hout + row * 16 + j), cv.s,
                           __ATOMIC_RELAXED, __HIP_MEMORY_SCOPE_AGENT);
      }
    }

    // ---- signal: drain stores to LLC, then bump own counter ----
    asm volatile("s_waitcnt vmcnt(0)" ::: "memory");
    __syncthreads();
    if (tid == 0)
      __hip_atomic_fetch_add(cown, 1u, __ATOMIC_RELAXED,
                             __HIP_MEMORY_SCOPE_AGENT);
  }
}

// ---------------------------------------------------------------------------
__global__ __launch_bounds__(64) void fc_kernel(
    const _Float16* __restrict__ hpl, const float* __restrict__ wfc,
    const float* __restrict__ bfc, float* __restrict__ out) {
  const _Float16* h = hpl + (size_t)(4 * NPAR + (127 & 3)) * PL;  // 19*PL
  const int b = blockIdx.x;
  const int lane = threadIdx.x;
  __shared__ float hrow[NH];
  for (int k = lane; k < NH; k += 64)
    hrow[k] = (float)h[(k >> 4) * 4096 + b * 16 + (k & 15)];
  __syncthreads();
  if (lane < NC) {
    const float* wv = wfc + (size_t)lane * NH;
    float acc = bfc[lane];
#pragma unroll 8
    for (int k = 0; k < NH; ++k) acc += hrow[k] * wv[k];
    out[b * NC + lane] = acc;
  }
}

// ---------------------------------------------------------------------------
extern "C" void kernel_launch(void* const* d_in, const int* in_sizes, int n_in,
                              void* d_out, int out_size, void* d_ws,
                              size_t ws_size, hipStream_t stream) {
  const float* x = (const float*)d_in[0];
  const float* Wih = (const float*)d_in[1];
  const float* Whh = (const float*)d_in[2];
  const float* bih = (const float*)d_in[3];
  const float* bhh = (const float*)d_in[4];
  const float* Wfc = (const float*)d_in[5];
  const float* bfc = (const float*)d_in[6];
  float* out = (float*)d_out;

  char* ws = (char*)d_ws;
  size_t off = 0;
  _Float16* xt = (_Float16*)(ws + off);
  off += (size_t)NT * PL * 2;                 // 33.5 MB
  _Float16* hpl = (_Float16*)(ws + off);
  off += (size_t)NL * NPAR * PL * 2;          // 5.2 MB
  off = (off + 255) & ~(size_t)255;
  unsigned* cnt = (unsigned*)(ws + off);
  off += 1024;

  hipFuncSetAttribute((const void*)lstm_persist,
                      hipFuncAttributeMaxDynamicSharedMemorySize, 131072);

  x_tile_kernel<<<NT * 32, 64, 0, stream>>>(x, xt);
  hipMemsetAsync(cnt, 0, 1024, stream);

  lstm_persist<<<GRID, 512, 131072, stream>>>(Wih, Whh, xt, bih, bhh, hpl,
                                              cnt);

  fc_kernel<<<NBATCH, 64, 0, stream>>>(hpl, Wfc, bfc, out);
}